// Round 22
// baseline (175.721 us; speedup 1.0000x reference)
//
#include <hip/hip_runtime.h>
#include <stdint.h>
#include <stddef.h>

// HardNegativeMiningLoss on MI355X (B=8192, D=512, K=16, TEMP=0.07, labels<2048).
// kconvh(bf16+init+hist/prefix/scatter fused) -> kpos2 -> kgemm (R20 config:
// BK=64, rows register-resident, Cg dbuf line-coalesced w/ both-sides swizzle,
// vmcnt(0), launch_bounds(256,2), + R21 wave-skip mining prescreen) -> kfin ->
// kfallA -> kout(+fallback finish).

#define TEMPV 0.07f
#define NEGV -1e30f

typedef short v8s __attribute__((ext_vector_type(8)));
typedef float v4f __attribute__((ext_vector_type(4)));

__device__ __forceinline__ short f2bf(float f) {
  unsigned u = __float_as_uint(f);
  unsigned r = (u + 0x7fffu + ((u >> 16) & 1u)) >> 16;  // RNE
  return (short)r;
}
__device__ __forceinline__ float bf2f(short s) {
  return __uint_as_float(((unsigned)(unsigned short)s) << 16);
}

__device__ __forceinline__ void gload16(const void* g, void* l) {
  __builtin_amdgcn_global_load_lds((const __attribute__((address_space(1))) unsigned*)g,
                                   (__attribute__((address_space(3))) unsigned*)l, 16, 0, 0);
}

// ---- Batcher odd-even mergesort network for 16 elements (63 comparators) ----
struct SNet { unsigned char a[64]; unsigned char b[64]; int n; };
constexpr SNet mknet16() {
  SNet t{}; t.n = 0;
  for (int p = 1; p < 16; p <<= 1)
    for (int k = p; k >= 1; k >>= 1)
      for (int j = k % p; j + k < 16; j += 2 * k)
        for (int i = 0; i < k; ++i) {
          int x = i + j, y = i + j + k;
          if (y < 16 && (x / (2 * p)) == (y / (2 * p))) {
            t.a[t.n] = (unsigned char)x; t.b[t.n] = (unsigned char)y; ++t.n;
          }
        }
  return t;
}
constexpr SNet NET16 = mknet16();
constexpr int NETN = NET16.n;

__device__ __forceinline__ void sort16d(float (&V)[16]) {
#pragma unroll
  for (int c = 0; c < NETN; ++c) {
    const int x = NET16.a[c], y = NET16.b[c];
    float hi = fmaxf(V[x], V[y]);
    float lo = fminf(V[x], V[y]);
    V[x] = hi; V[y] = lo;
  }
}

// clean a bitonic 16-seq into descending order
__device__ __forceinline__ void clean16d(float (&V)[16]) {
#pragma unroll
  for (int s = 8; s >= 1; s >>= 1) {
#pragma unroll
    for (int i = 0; i < 16; ++i) {
      if ((i & s) == 0) {
        float hi = fmaxf(V[i], V[i + s]);
        float lo = fminf(V[i], V[i + s]);
        V[i] = hi; V[i + s] = lo;
      }
    }
  }
}

// R = top16(R ∪ M), both desc sorted; in-place
__device__ __forceinline__ void mergeld(float (&R)[16], const float (&M)[16]) {
#pragma unroll
  for (int i = 0; i < 8; ++i) {
    float a = fmaxf(M[i], R[15 - i]);
    float b = fmaxf(M[15 - i], R[i]);
    R[i] = a; R[15 - i] = b;
  }
  clean16d(R);
}

// merge my desc-16 with xor-partner lane's desc-16 (both get top-16 of union)
__device__ __forceinline__ void xmerge16(float (&M)[16], int mask) {
#pragma unroll
  for (int i = 0; i < 8; ++i) {
    float pa = __shfl_xor(M[15 - i], mask);
    float pb = __shfl_xor(M[i], mask);
    M[i] = fmaxf(M[i], pa);
    M[15 - i] = fmaxf(M[15 - i], pb);
  }
  clean16d(M);
}

// ascending top-16 insert list (serial guard path only): call when v > L[0]
__device__ __forceinline__ void ins16(float (&L)[16], float v) {
#pragma unroll
  for (int k = 0; k < 15; ++k) {
    float lo = fminf(v, L[k + 1]);
    float hi = fmaxf(v, L[k + 1]);
    L[k] = lo;
    v = hi;
  }
  L[15] = v;
}

// ---------------- fused setup kernel ----------------
// blocks 0..4095: bf16 convert (block 0 also zero-inits scalars);
// block 4096: LDS histogram -> prefix -> scatter (runs concurrently with conv).
__global__ __launch_bounds__(256) void kconvh(const float* __restrict__ emb,
                                              short* __restrict__ emb16,
                                              const int* __restrict__ lab,
                                              int* __restrict__ hist,
                                              int* __restrict__ start,
                                              int* __restrict__ rows,
                                              float* lsum, int* nval, int* fbcnt) {
  __shared__ int h[2048];
  __shared__ int part[256];
  int t = threadIdx.x;
  if (blockIdx.x < 4096) {
    int i = (blockIdx.x * 256 + t) * 4;
    float4 v = *(const float4*)(emb + i);
    short4 s;
    s.x = f2bf(v.x); s.y = f2bf(v.y); s.z = f2bf(v.z); s.w = f2bf(v.w);
    *(short4*)(emb16 + i) = s;
    if (blockIdx.x == 0 && t == 0) { *lsum = 0.f; *nval = 0; *fbcnt = 0; }
    return;
  }
  // block 4096: hist/prefix/scatter
#pragma unroll
  for (int k = 0; k < 8; ++k) h[t * 8 + k] = 0;
  __syncthreads();
  for (int i = t; i < 8192; i += 256) atomicAdd(&h[lab[i]], 1);
  __syncthreads();
  int v[8], loc[8], s = 0;
#pragma unroll
  for (int k = 0; k < 8; ++k) v[k] = h[t * 8 + k];
#pragma unroll
  for (int k = 0; k < 8; ++k) { loc[k] = s; s += v[k]; }
  part[t] = s;
  __syncthreads();
  for (int off = 1; off < 256; off <<= 1) {
    int x = (t >= off) ? part[t - off] : 0;
    __syncthreads();
    part[t] += x;
    __syncthreads();
  }
  int base = (t > 0) ? part[t - 1] : 0;
#pragma unroll
  for (int k = 0; k < 8; ++k) {
    hist[t * 8 + k] = v[k];
    start[t * 8 + k] = base + loc[k];
  }
  __syncthreads();
#pragma unroll
  for (int k = 0; k < 8; ++k) h[t * 8 + k] = base + loc[k];
  __syncthreads();
  for (int i = t; i < 8192; i += 256) {
    int p = atomicAdd(&h[lab[i]], 1);
    rows[p] = i;
  }
}

__global__ __launch_bounds__(256) void kpos2(const short* __restrict__ emb16,
                                             const int* __restrict__ lab,
                                             const int* __restrict__ hist,
                                             const int* __restrict__ start,
                                             const int* __restrict__ rows,
                                             float* __restrict__ pmin,
                                             float* __restrict__ pterm,
                                             int* __restrict__ valid) {
  int t = threadIdx.x;
  int wv = t >> 6, lane = t & 63;
  int i = blockIdx.x * 4 + wv;
  int li = lab[i];
  int s0 = start[li], c = hist[li];
  float ei[8];
  v8s e = *(const v8s*)(emb16 + (size_t)i * 512 + lane * 8);
#pragma unroll
  for (int k = 0; k < 8; ++k) ei[k] = bf2f(e[k]);
  float smin = 1e30f, ssum = 0.f;
  for (int k = 0; k < c; ++k) {
    int j = rows[s0 + k];
    if (j == i) continue;
    v8s f = *(const v8s*)(emb16 + (size_t)j * 512 + lane * 8);
    float s = 0.f;
#pragma unroll
    for (int q = 0; q < 8; ++q) s += ei[q] * bf2f(f[q]);
#pragma unroll
    for (int off = 32; off; off >>= 1) s += __shfl_xor(s, off);
    smin = fminf(smin, s);
    ssum += s;
  }
  if (lane == 0) {
    int pc = c - 1, nc = 8192 - c;
    pmin[i] = smin;                                   // +1e30 when no positives
    pterm[i] = ssum / (float)(pc > 0 ? pc : 1) / TEMPV;
    valid[i] = (pc > 0 && nc > 0) ? 1 : 0;
  }
}

// ---------------- main mining GEMM (R20 config + prescreen) ----------------
// Grid 1024 = 128 row-blocks(BM=64) x 8 col-blocks (1024 cols; cb=bid&7 -> XCD).
// 4 waves stacked on rows: wave rows = wv*16 + l15 (16 rows/wave). Each thread
// holds its row's FULL K=512 in brow[8][2] (16 v8s = 64 VGPR), loaded ONCE.
// 64 stages = 8 col-tiles(128) x 8 K64-steps. Cg dbuf 2x[128col][64K] = 32KB,
// line-coalesced fully-used 64B lines; both-sides swizzle ch^=(col&7), read pos
// (h*4+l4)^(l15&7). Per stage: ds_read 16 a-frags -> issue Cg(s+1) (4 gload_lds)
// -> setprio(1) 16 MFMA setprio(0) -> [mine at kst==7, wave-skip prescreen] ->
// vmcnt(0) (full-stage cover) -> s_barrier.
// acc[mi][r] = sim[wv*16+l15][ct*128 + mi*16 + l4*4 + r].
__global__ __launch_bounds__(256, 2) void kgemm(const short* __restrict__ emb16,
                                                const int* __restrict__ lab,
                                                const float* __restrict__ pminA,
                                                float* __restrict__ Lsemi) {
  __shared__ __align__(16) short Cg[2][128][64];  // 32KB

  int t = threadIdx.x;
  int bid = blockIdx.x;
  int rb = bid >> 3, cb = bid & 7;
  int rowbase = rb * 64;
  int colblock = cb * 1024;

  int wv = t >> 6, l = t & 63;
  int l15 = l & 15, l4 = l >> 4;

  int myrow = rowbase + wv * 16 + l15;
  int rlab = lab[myrow];
  float pm = pminA[myrow];

  // full-K row residency: 16 v8s = 64 VGPR, loaded once (all static indices)
  v8s brow[8][2];
#pragma unroll
  for (int kst = 0; kst < 8; ++kst)
#pragma unroll
    for (int h = 0; h < 2; ++h)
      brow[kst][h] =
          *(const v8s*)(emb16 + (size_t)myrow * 512 + kst * 64 + h * 32 + l4 * 8);

  float RS[16];
#pragma unroll
  for (int k = 0; k < 16; ++k) RS[k] = NEGV;

  v4f acc[8];
#pragma unroll
  for (int mi = 0; mi < 8; ++mi) acc[mi] = (v4f)0.f;

  // prologue: Cg stage-0 (cols colblock..+128, K 0..64)
#pragma unroll
  for (int q = 0; q < 4; ++q) {
    int e = q * 256 + t;
    int col = e >> 3, ch = e & 7;
    gload16(emb16 + ((size_t)(colblock + col) * 512 + ((ch ^ (col & 7)) * 8)),
            &Cg[0][col][ch * 8]);
  }
  asm volatile("s_waitcnt vmcnt(0)" ::: "memory");
  __builtin_amdgcn_s_barrier();

  const int apos0 = (l4 ^ (l15 & 7)) * 8;  // read chunk pos, h=0 (h=1: ^32)

  for (int ct = 0; ct < 8; ++ct) {
#pragma unroll
    for (int kst = 0; kst < 8; ++kst) {
      const int cur = kst & 1;  // stage parity (ct*8 even)
      // (1) ds_read all 16 a-frags of the current buffer (before new LDS writes)
      v8s a0[8], a1[8];
#pragma unroll
      for (int mi = 0; mi < 8; ++mi)
        a0[mi] = *(const v8s*)&Cg[cur][mi * 16 + l15][apos0];
#pragma unroll
      for (int mi = 0; mi < 8; ++mi)
        a1[mi] = *(const v8s*)&Cg[cur][mi * 16 + l15][apos0 ^ 32];
      // (2) issue next stage's Cg loads into the other buffer
      if (!(ct == 7 && kst == 7)) {
        const int nct = (kst == 7) ? ct + 1 : ct;
        const int nk = ((kst + 1) & 7) * 64;
#pragma unroll
        for (int q = 0; q < 4; ++q) {
          int e = q * 256 + t;
          int col = e >> 3, ch = e & 7;
          gload16(emb16 + ((size_t)(colblock + nct * 128 + col) * 512 + nk +
                           ((ch ^ (col & 7)) * 8)),
                  &Cg[cur ^ 1][col][ch * 8]);
        }
      }
      // (3) MFMA cluster (register-only), wave-priority boosted
      __builtin_amdgcn_s_setprio(1);
#pragma unroll
      for (int mi = 0; mi < 8; ++mi)
        acc[mi] = __builtin_amdgcn_mfma_f32_16x16x32_bf16(a0[mi], brow[kst][0],
                                                          acc[mi], 0, 0, 0);
#pragma unroll
      for (int mi = 0; mi < 8; ++mi)
        acc[mi] = __builtin_amdgcn_mfma_f32_16x16x32_bf16(a1[mi], brow[kst][1],
                                                          acc[mi], 0, 0, 0);
      __builtin_amdgcn_s_setprio(0);
      // (4) mine at col-tile end (full-K sums), wave-skip prescreen
      if (kst == 7) {
        const int mycolbase = colblock + ct * 128;
#pragma unroll
        for (int c = 0; c < 2; ++c) {
          int lc[4][4];
#pragma unroll
          for (int mm = 0; mm < 4; ++mm) {
            int4 q = *(const int4*)&lab[mycolbase + (c * 4 + mm) * 16 + l4 * 4];
            lc[mm][0] = q.x; lc[mm][1] = q.y; lc[mm][2] = q.z; lc[mm][3] = q.w;
          }
          float S[16];
#pragma unroll
          for (int j = 0; j < 16; ++j) {
            const int mi = c * 4 + (j >> 2), r = j & 3;
            float v = acc[mi][r];
            bool keep = (lc[j >> 2][r] != rlab) && (v < pm);
            S[j] = keep ? v : NEGV;
          }
          // prescreen: skip sort+merge if no lane's batch can enter its top-16
          float vm = S[0];
#pragma unroll
          for (int j = 1; j < 16; ++j) vm = fmaxf(vm, S[j]);
          if (__any(vm > RS[15])) {   // mergeld is a no-op for all-smaller M
            sort16d(S);
            mergeld(RS, S);
          }
        }
#pragma unroll
        for (int mi = 0; mi < 8; ++mi) acc[mi] = (v4f)0.f;
      }
      // (5) drain the in-flight Cg stage (covered by MFMA/mining), barrier
      asm volatile("s_waitcnt vmcnt(0)" ::: "memory");
      __builtin_amdgcn_s_barrier();
    }
  }

  // cross-lane merge (4 l4-groups share each row); rows are wave-exclusive
  xmerge16(RS, 16);
  xmerge16(RS, 32);
  if (l4 == 0) {
    size_t o = ((size_t)cb * 8192 + myrow) * 16;
#pragma unroll
    for (int k = 0; k < 4; ++k)
      *(float4*)&Lsemi[o + k * 4] =
          make_float4(RS[k * 4], RS[k * 4 + 1], RS[k * 4 + 2], RS[k * 4 + 3]);
  }
}

// merge 8 col-block semi partials, masked LSE, detect fallback rows, reduce
__global__ __launch_bounds__(256) void kfin(const float* __restrict__ Lsemi,
                                            const float* __restrict__ pterm,
                                            const int* __restrict__ valid,
                                            float* lsum, int* nval,
                                            int* fbcnt, int* fbrows) {
  int i = blockIdx.x * 256 + threadIdx.x;
  float S[16], M[16];
#pragma unroll
  for (int k = 0; k < 16; ++k) S[k] = Lsemi[(size_t)i * 16 + k];
  for (int c = 1; c < 8; ++c) {
    size_t o = ((size_t)c * 8192 + i) * 16;
#pragma unroll
    for (int k = 0; k < 16; ++k) M[k] = Lsemi[o + k];
    mergeld(S, M);
  }
  int vd = valid[i];
  bool hs = S[0] > -1e29f;
  float li = 0.f;
  if (vd && !hs) {
    int idx = atomicAdd(fbcnt, 1);
    fbrows[idx] = i;          // loss added by kout's fallback pass
  } else if (vd) {
    float m = S[0] / TEMPV;
    float se = 0.f;
#pragma unroll
    for (int k = 0; k < 16; ++k)
      if (S[k] > -1e29f) se += expf(S[k] / TEMPV - m);
    li = m + logf(se) - pterm[i];
  }
#pragma unroll
  for (int off = 32; off; off >>= 1) {
    li += __shfl_xor(li, off);
    vd += __shfl_xor(vd, off);
  }
  __shared__ float rsd[4];
  __shared__ int rid[4];
  int wv = threadIdx.x >> 6;
  if ((threadIdx.x & 63) == 0) { rsd[wv] = li; rid[wv] = vd; }
  __syncthreads();
  if (threadIdx.x == 0) {
    atomicAdd(lsum, rsd[0] + rsd[1] + rsd[2] + rsd[3]);
    atomicAdd(nval, rid[0] + rid[1] + rid[2] + rid[3]);
  }
}

// Parallel fallback phase A: unit u = (f, j) -> row fbrows[f], candidates
// [j*256, j*256+256). One candidate/thread; 8 independent FMA chains (ILP).
__global__ __launch_bounds__(256) void kfallA(const short* __restrict__ emb16,
                                              const int* __restrict__ lab,
                                              const int* __restrict__ fbcnt,
                                              const int* __restrict__ fbrows,
                                              float* __restrict__ fbpart) {
  int nfb = *fbcnt;
  if (nfb > 2048) nfb = 2048;
  int nunits = nfb * 32;
  __shared__ short remb[512];
  __shared__ float sims[256];
  int t = threadIdx.x;
  for (int u = blockIdx.x; u < nunits; u += gridDim.x) {
    int f = u >> 5, j = u & 31;
    int row = fbrows[f];
    int rl = lab[row];
    __syncthreads();  // prior iteration's reads of remb/sims complete
    if (t < 64) *(v8s*)&remb[t * 8] = *(const v8s*)(emb16 + (size_t)row * 512 + t * 8);
    __syncthreads();
    int c = j * 256 + t;
    float sz[8];
#pragma unroll
    for (int z = 0; z < 8; ++z) sz[z] = 0.f;
#pragma unroll 4
    for (int q = 0; q < 64; ++q) {
      v8s e = *(const v8s*)(emb16 + (size_t)c * 512 + q * 8);
      v8s r = *(const v8s*)&remb[q * 8];
#pragma unroll
      for (int z = 0; z < 8; ++z) sz[z] += bf2f(e[z]) * bf2f(r[z]);
    }
    float s = ((sz[0] + sz[1]) + (sz[2] + sz[3])) + ((sz[4] + sz[5]) + (sz[6] + sz[7]));
    sims[t] = (lab[c] != rl) ? s : NEGV;
    __syncthreads();
    if (t < 64) {
      float M[16];
#pragma unroll
      for (int k = 0; k < 16; ++k) M[k] = NEGV;
      M[0] = sims[t]; M[1] = sims[64 + t]; M[2] = sims[128 + t]; M[3] = sims[192 + t];
      sort16d(M);
      xmerge16(M, 1); xmerge16(M, 2); xmerge16(M, 4);
      xmerge16(M, 8); xmerge16(M, 16); xmerge16(M, 32);
      if (t == 0) {
#pragma unroll
        for (int k = 0; k < 16; ++k) fbpart[(size_t)(f * 32 + j) * 16 + k] = M[k];
      }
    }
  }
}

// Final kernel: finish fallback rows (merge 32 partials each, LSE, accumulate)
// then write out = (lsum + fb_sum) / nval. Single block.
__global__ __launch_bounds__(256) void kout(const short* __restrict__ emb16,
                                            const int* __restrict__ lab,
                                            const int* __restrict__ fbcnt,
                                            const int* __restrict__ fbrows,
                                            const float* __restrict__ fbpart,
                                            const float* __restrict__ pterm,
                                            const float* lsum, const int* nval,
                                            float* out) {
  __shared__ float fsum[256];
  int t = threadIdx.x;
  int nfb = *fbcnt;
  float acc = 0.f;
  for (int f = t; f < nfb; f += 256) {
    int row = fbrows[f];
    float R[16];
    if (f < 2048) {
#pragma unroll
      for (int k = 0; k < 16; ++k) R[k] = fbpart[(size_t)(f * 32) * 16 + k];
      for (int j = 1; j < 32; ++j) {
        float M[16];
#pragma unroll
        for (int k = 0; k < 16; ++k) M[k] = fbpart[(size_t)(f * 32 + j) * 16 + k];
        mergeld(R, M);
      }
    } else {
      // correctness guard; never expected to execute
      int rl = lab[row];
      float L[16];
#pragma unroll
      for (int k = 0; k < 16; ++k) L[k] = NEGV;
      for (int c = 0; c < 8192; ++c) {
        if (lab[c] == rl) continue;
        float s = 0.f;
        for (int q = 0; q < 64; ++q) {
          v8s e = *(const v8s*)(emb16 + (size_t)c * 512 + q * 8);
          v8s r = *(const v8s*)(emb16 + (size_t)row * 512 + q * 8);
#pragma unroll
          for (int z = 0; z < 8; ++z) s += bf2f(e[z]) * bf2f(r[z]);
        }
        if (s > L[0]) ins16(L, s);
      }
#pragma unroll
      for (int k = 0; k < 16; ++k) R[k] = L[15 - k];
    }
    float m = R[0] / TEMPV;
    float se = 0.f;
#pragma unroll
    for (int k = 0; k < 16; ++k)
      if (R[k] > -1e29f) se += expf(R[k] / TEMPV - m);
    acc += m + logf(se) - pterm[row];
  }
  fsum[t] = acc;
  __syncthreads();
  if (t == 0) {
    float s = *lsum;
    for (int k = 0; k < 256; ++k) s += fsum[k];
    int n = *nval;
    out[0] = s / (float)(n > 0 ? n : 1);
  }
}

extern "C" void kernel_launch(void* const* d_in, const int* in_sizes, int n_in,
                              void* d_out, int out_size, void* d_ws, size_t ws_size,
                              hipStream_t stream) {
  const float* emb = (const float*)d_in[0];
  const int* lab = (const int*)d_in[1];
  float* out = (float*)d_out;

  char* wsb = (char*)d_ws;
  short* emb16 = (short*)wsb;                       // 8,388,608
  int* hist = (int*)(wsb + 8388608);                // 8,192
  int* start = (int*)(wsb + 8396800);               // 8,192
  int* rows = (int*)(wsb + 8404992);                // 32,768
  float* pmin = (float*)(wsb + 8437760);            // 32,768
  float* pterm = (float*)(wsb + 8470528);           // 32,768
  int* valid = (int*)(wsb + 8503296);               // 32,768
  float* LsemiW = (float*)(wsb + 8536064);          // 4,194,304 (8 partials)
  int* fbcnt = (int*)(wsb + 12730368);              // 4 (+pad 64)
  int* fbrows = (int*)(wsb + 12730432);             // 32,768
  float* fbpart = (float*)(wsb + 12763200);         // 4,194,304
  float* lsum = (float*)(wsb + 16957504);           // 4
  int* nval = (int*)(wsb + 16957508);               // 4

  kconvh<<<4097, 256, 0, stream>>>(emb, emb16, lab, hist, start, rows, lsum, nval, fbcnt);
  kpos2<<<2048, 256, 0, stream>>>(emb16, lab, hist, start, rows, pmin, pterm, valid);
  kgemm<<<1024, 256, 0, stream>>>(emb16, lab, pmin, LsemiW);
  kfin<<<32, 256, 0, stream>>>(LsemiW, pterm, valid, lsum, nval, fbcnt, fbrows);
  kfallA<<<256, 256, 0, stream>>>(emb16, lab, fbcnt, fbrows, fbpart);
  kout<<<1, 256, 0, stream>>>(emb16, lab, fbcnt, fbrows, fbpart, pterm, lsum, nval, out);
}

// Round 23
// 172.960 us; speedup vs baseline: 1.0160x; 1.0160x over previous
//
#include <hip/hip_runtime.h>
#include <stdint.h>
#include <stddef.h>

// HardNegativeMiningLoss on MI355X (B=8192, D=512, K=16, TEMP=0.07, labels<2048).
// FINAL CONFIG (best measured: 175.1us total, kgemm 109-112us):
// kconvh(bf16+init+hist/prefix/scatter fused) -> kpos2 -> kgemm (BK=64, rows
// register-resident, Cg dbuf line-coalesced w/ both-sides swizzle, vmcnt(0),
// launch_bounds(256,2) -> VGPR 108, no spill) -> kfin -> kfallA -> kout(+fb).

#define TEMPV 0.07f
#define NEGV -1e30f

typedef short v8s __attribute__((ext_vector_type(8)));
typedef float v4f __attribute__((ext_vector_type(4)));

__device__ __forceinline__ short f2bf(float f) {
  unsigned u = __float_as_uint(f);
  unsigned r = (u + 0x7fffu + ((u >> 16) & 1u)) >> 16;  // RNE
  return (short)r;
}
__device__ __forceinline__ float bf2f(short s) {
  return __uint_as_float(((unsigned)(unsigned short)s) << 16);
}

__device__ __forceinline__ void gload16(const void* g, void* l) {
  __builtin_amdgcn_global_load_lds((const __attribute__((address_space(1))) unsigned*)g,
                                   (__attribute__((address_space(3))) unsigned*)l, 16, 0, 0);
}

// ---- Batcher odd-even mergesort network for 16 elements (63 comparators) ----
struct SNet { unsigned char a[64]; unsigned char b[64]; int n; };
constexpr SNet mknet16() {
  SNet t{}; t.n = 0;
  for (int p = 1; p < 16; p <<= 1)
    for (int k = p; k >= 1; k >>= 1)
      for (int j = k % p; j + k < 16; j += 2 * k)
        for (int i = 0; i < k; ++i) {
          int x = i + j, y = i + j + k;
          if (y < 16 && (x / (2 * p)) == (y / (2 * p))) {
            t.a[t.n] = (unsigned char)x; t.b[t.n] = (unsigned char)y; ++t.n;
          }
        }
  return t;
}
constexpr SNet NET16 = mknet16();
constexpr int NETN = NET16.n;

__device__ __forceinline__ void sort16d(float (&V)[16]) {
#pragma unroll
  for (int c = 0; c < NETN; ++c) {
    const int x = NET16.a[c], y = NET16.b[c];
    float hi = fmaxf(V[x], V[y]);
    float lo = fminf(V[x], V[y]);
    V[x] = hi; V[y] = lo;
  }
}

// clean a bitonic 16-seq into descending order
__device__ __forceinline__ void clean16d(float (&V)[16]) {
#pragma unroll
  for (int s = 8; s >= 1; s >>= 1) {
#pragma unroll
    for (int i = 0; i < 16; ++i) {
      if ((i & s) == 0) {
        float hi = fmaxf(V[i], V[i + s]);
        float lo = fminf(V[i], V[i + s]);
        V[i] = hi; V[i + s] = lo;
      }
    }
  }
}

// R = top16(R ∪ M), both desc sorted; in-place
__device__ __forceinline__ void mergeld(float (&R)[16], const float (&M)[16]) {
#pragma unroll
  for (int i = 0; i < 8; ++i) {
    float a = fmaxf(M[i], R[15 - i]);
    float b = fmaxf(M[15 - i], R[i]);
    R[i] = a; R[15 - i] = b;
  }
  clean16d(R);
}

// merge my desc-16 with xor-partner lane's desc-16 (both get top-16 of union)
__device__ __forceinline__ void xmerge16(float (&M)[16], int mask) {
#pragma unroll
  for (int i = 0; i < 8; ++i) {
    float pa = __shfl_xor(M[15 - i], mask);
    float pb = __shfl_xor(M[i], mask);
    M[i] = fmaxf(M[i], pa);
    M[15 - i] = fmaxf(M[15 - i], pb);
  }
  clean16d(M);
}

// ascending top-16 insert list (serial guard path only): call when v > L[0]
__device__ __forceinline__ void ins16(float (&L)[16], float v) {
#pragma unroll
  for (int k = 0; k < 15; ++k) {
    float lo = fminf(v, L[k + 1]);
    float hi = fmaxf(v, L[k + 1]);
    L[k] = lo;
    v = hi;
  }
  L[15] = v;
}

// ---------------- fused setup kernel ----------------
// blocks 0..4095: bf16 convert (block 0 also zero-inits scalars);
// block 4096: LDS histogram -> prefix -> scatter (runs concurrently with conv).
__global__ __launch_bounds__(256) void kconvh(const float* __restrict__ emb,
                                              short* __restrict__ emb16,
                                              const int* __restrict__ lab,
                                              int* __restrict__ hist,
                                              int* __restrict__ start,
                                              int* __restrict__ rows,
                                              float* lsum, int* nval, int* fbcnt) {
  __shared__ int h[2048];
  __shared__ int part[256];
  int t = threadIdx.x;
  if (blockIdx.x < 4096) {
    int i = (blockIdx.x * 256 + t) * 4;
    float4 v = *(const float4*)(emb + i);
    short4 s;
    s.x = f2bf(v.x); s.y = f2bf(v.y); s.z = f2bf(v.z); s.w = f2bf(v.w);
    *(short4*)(emb16 + i) = s;
    if (blockIdx.x == 0 && t == 0) { *lsum = 0.f; *nval = 0; *fbcnt = 0; }
    return;
  }
  // block 4096: hist/prefix/scatter
#pragma unroll
  for (int k = 0; k < 8; ++k) h[t * 8 + k] = 0;
  __syncthreads();
  for (int i = t; i < 8192; i += 256) atomicAdd(&h[lab[i]], 1);
  __syncthreads();
  int v[8], loc[8], s = 0;
#pragma unroll
  for (int k = 0; k < 8; ++k) v[k] = h[t * 8 + k];
#pragma unroll
  for (int k = 0; k < 8; ++k) { loc[k] = s; s += v[k]; }
  part[t] = s;
  __syncthreads();
  for (int off = 1; off < 256; off <<= 1) {
    int x = (t >= off) ? part[t - off] : 0;
    __syncthreads();
    part[t] += x;
    __syncthreads();
  }
  int base = (t > 0) ? part[t - 1] : 0;
#pragma unroll
  for (int k = 0; k < 8; ++k) {
    hist[t * 8 + k] = v[k];
    start[t * 8 + k] = base + loc[k];
  }
  __syncthreads();
#pragma unroll
  for (int k = 0; k < 8; ++k) h[t * 8 + k] = base + loc[k];
  __syncthreads();
  for (int i = t; i < 8192; i += 256) {
    int p = atomicAdd(&h[lab[i]], 1);
    rows[p] = i;
  }
}

__global__ __launch_bounds__(256) void kpos2(const short* __restrict__ emb16,
                                             const int* __restrict__ lab,
                                             const int* __restrict__ hist,
                                             const int* __restrict__ start,
                                             const int* __restrict__ rows,
                                             float* __restrict__ pmin,
                                             float* __restrict__ pterm,
                                             int* __restrict__ valid) {
  int t = threadIdx.x;
  int wv = t >> 6, lane = t & 63;
  int i = blockIdx.x * 4 + wv;
  int li = lab[i];
  int s0 = start[li], c = hist[li];
  float ei[8];
  v8s e = *(const v8s*)(emb16 + (size_t)i * 512 + lane * 8);
#pragma unroll
  for (int k = 0; k < 8; ++k) ei[k] = bf2f(e[k]);
  float smin = 1e30f, ssum = 0.f;
  for (int k = 0; k < c; ++k) {
    int j = rows[s0 + k];
    if (j == i) continue;
    v8s f = *(const v8s*)(emb16 + (size_t)j * 512 + lane * 8);
    float s = 0.f;
#pragma unroll
    for (int q = 0; q < 8; ++q) s += ei[q] * bf2f(f[q]);
#pragma unroll
    for (int off = 32; off; off >>= 1) s += __shfl_xor(s, off);
    smin = fminf(smin, s);
    ssum += s;
  }
  if (lane == 0) {
    int pc = c - 1, nc = 8192 - c;
    pmin[i] = smin;                                   // +1e30 when no positives
    pterm[i] = ssum / (float)(pc > 0 ? pc : 1) / TEMPV;
    valid[i] = (pc > 0 && nc > 0) ? 1 : 0;
  }
}

// ---------------- main mining GEMM (final config) ----------------
// Grid 1024 = 128 row-blocks(BM=64) x 8 col-blocks (1024 cols; cb=bid&7 -> XCD).
// 4 waves stacked on rows: wave rows = wv*16 + l15 (16 rows/wave). Each thread
// holds its row's FULL K=512 in brow[8][2] (16 v8s = 64 VGPR), loaded ONCE.
// 64 stages = 8 col-tiles(128) x 8 K64-steps. Cg dbuf 2x[128col][64K] = 32KB,
// line-coalesced fully-used 64B lines; both-sides swizzle ch^=(col&7), read pos
// (h*4+l4)^(l15&7). Per stage: ds_read 16 a-frags -> issue Cg(s+1) (4 gload_lds)
// -> setprio(1) 16 MFMA setprio(0) -> [mine at kst==7] -> vmcnt(0) (full-stage
// cover) -> s_barrier. acc[mi][r] = sim[wv*16+l15][ct*128 + mi*16 + l4*4 + r].
__global__ __launch_bounds__(256, 2) void kgemm(const short* __restrict__ emb16,
                                                const int* __restrict__ lab,
                                                const float* __restrict__ pminA,
                                                float* __restrict__ Lsemi) {
  __shared__ __align__(16) short Cg[2][128][64];  // 32KB

  int t = threadIdx.x;
  int bid = blockIdx.x;
  int rb = bid >> 3, cb = bid & 7;
  int rowbase = rb * 64;
  int colblock = cb * 1024;

  int wv = t >> 6, l = t & 63;
  int l15 = l & 15, l4 = l >> 4;

  int myrow = rowbase + wv * 16 + l15;
  int rlab = lab[myrow];
  float pm = pminA[myrow];

  // full-K row residency: 16 v8s = 64 VGPR, loaded once (all static indices)
  v8s brow[8][2];
#pragma unroll
  for (int kst = 0; kst < 8; ++kst)
#pragma unroll
    for (int h = 0; h < 2; ++h)
      brow[kst][h] =
          *(const v8s*)(emb16 + (size_t)myrow * 512 + kst * 64 + h * 32 + l4 * 8);

  float RS[16];
#pragma unroll
  for (int k = 0; k < 16; ++k) RS[k] = NEGV;

  v4f acc[8];
#pragma unroll
  for (int mi = 0; mi < 8; ++mi) acc[mi] = (v4f)0.f;

  // prologue: Cg stage-0 (cols colblock..+128, K 0..64)
#pragma unroll
  for (int q = 0; q < 4; ++q) {
    int e = q * 256 + t;
    int col = e >> 3, ch = e & 7;
    gload16(emb16 + ((size_t)(colblock + col) * 512 + ((ch ^ (col & 7)) * 8)),
            &Cg[0][col][ch * 8]);
  }
  asm volatile("s_waitcnt vmcnt(0)" ::: "memory");
  __builtin_amdgcn_s_barrier();

  const int apos0 = (l4 ^ (l15 & 7)) * 8;  // read chunk pos, h=0 (h=1: ^32)

  for (int ct = 0; ct < 8; ++ct) {
#pragma unroll
    for (int kst = 0; kst < 8; ++kst) {
      const int cur = kst & 1;  // stage parity (ct*8 even)
      // (1) ds_read all 16 a-frags of the current buffer (before new LDS writes)
      v8s a0[8], a1[8];
#pragma unroll
      for (int mi = 0; mi < 8; ++mi)
        a0[mi] = *(const v8s*)&Cg[cur][mi * 16 + l15][apos0];
#pragma unroll
      for (int mi = 0; mi < 8; ++mi)
        a1[mi] = *(const v8s*)&Cg[cur][mi * 16 + l15][apos0 ^ 32];
      // (2) issue next stage's Cg loads into the other buffer
      if (!(ct == 7 && kst == 7)) {
        const int nct = (kst == 7) ? ct + 1 : ct;
        const int nk = ((kst + 1) & 7) * 64;
#pragma unroll
        for (int q = 0; q < 4; ++q) {
          int e = q * 256 + t;
          int col = e >> 3, ch = e & 7;
          gload16(emb16 + ((size_t)(colblock + nct * 128 + col) * 512 + nk +
                           ((ch ^ (col & 7)) * 8)),
                  &Cg[cur ^ 1][col][ch * 8]);
        }
      }
      // (3) MFMA cluster (register-only), wave-priority boosted
      __builtin_amdgcn_s_setprio(1);
#pragma unroll
      for (int mi = 0; mi < 8; ++mi)
        acc[mi] = __builtin_amdgcn_mfma_f32_16x16x32_bf16(a0[mi], brow[kst][0],
                                                          acc[mi], 0, 0, 0);
#pragma unroll
      for (int mi = 0; mi < 8; ++mi)
        acc[mi] = __builtin_amdgcn_mfma_f32_16x16x32_bf16(a1[mi], brow[kst][1],
                                                          acc[mi], 0, 0, 0);
      __builtin_amdgcn_s_setprio(0);
      // (4) mine at col-tile end (full-K sums); VALU covers the in-flight stage
      if (kst == 7) {
        const int mycolbase = colblock + ct * 128;
#pragma unroll
        for (int c = 0; c < 2; ++c) {
          int lc[4][4];
#pragma unroll
          for (int mm = 0; mm < 4; ++mm) {
            int4 q = *(const int4*)&lab[mycolbase + (c * 4 + mm) * 16 + l4 * 4];
            lc[mm][0] = q.x; lc[mm][1] = q.y; lc[mm][2] = q.z; lc[mm][3] = q.w;
          }
          float S[16];
#pragma unroll
          for (int j = 0; j < 16; ++j) {
            const int mi = c * 4 + (j >> 2), r = j & 3;
            float v = acc[mi][r];
            bool keep = (lc[j >> 2][r] != rlab) && (v < pm);
            S[j] = keep ? v : NEGV;
          }
          sort16d(S);
          mergeld(RS, S);
        }
#pragma unroll
        for (int mi = 0; mi < 8; ++mi) acc[mi] = (v4f)0.f;
      }
      // (5) drain the in-flight Cg stage (covered by MFMA/mining), barrier
      asm volatile("s_waitcnt vmcnt(0)" ::: "memory");
      __builtin_amdgcn_s_barrier();
    }
  }

  // cross-lane merge (4 l4-groups share each row); rows are wave-exclusive
  xmerge16(RS, 16);
  xmerge16(RS, 32);
  if (l4 == 0) {
    size_t o = ((size_t)cb * 8192 + myrow) * 16;
#pragma unroll
    for (int k = 0; k < 4; ++k)
      *(float4*)&Lsemi[o + k * 4] =
          make_float4(RS[k * 4], RS[k * 4 + 1], RS[k * 4 + 2], RS[k * 4 + 3]);
  }
}

// merge 8 col-block semi partials, masked LSE, detect fallback rows, reduce
__global__ __launch_bounds__(256) void kfin(const float* __restrict__ Lsemi,
                                            const float* __restrict__ pterm,
                                            const int* __restrict__ valid,
                                            float* lsum, int* nval,
                                            int* fbcnt, int* fbrows) {
  int i = blockIdx.x * 256 + threadIdx.x;
  float S[16], M[16];
#pragma unroll
  for (int k = 0; k < 16; ++k) S[k] = Lsemi[(size_t)i * 16 + k];
  for (int c = 1; c < 8; ++c) {
    size_t o = ((size_t)c * 8192 + i) * 16;
#pragma unroll
    for (int k = 0; k < 16; ++k) M[k] = Lsemi[o + k];
    mergeld(S, M);
  }
  int vd = valid[i];
  bool hs = S[0] > -1e29f;
  float li = 0.f;
  if (vd && !hs) {
    int idx = atomicAdd(fbcnt, 1);
    fbrows[idx] = i;          // loss added by kout's fallback pass
  } else if (vd) {
    float m = S[0] / TEMPV;
    float se = 0.f;
#pragma unroll
    for (int k = 0; k < 16; ++k)
      if (S[k] > -1e29f) se += expf(S[k] / TEMPV - m);
    li = m + logf(se) - pterm[i];
  }
#pragma unroll
  for (int off = 32; off; off >>= 1) {
    li += __shfl_xor(li, off);
    vd += __shfl_xor(vd, off);
  }
  __shared__ float rsd[4];
  __shared__ int rid[4];
  int wv = threadIdx.x >> 6;
  if ((threadIdx.x & 63) == 0) { rsd[wv] = li; rid[wv] = vd; }
  __syncthreads();
  if (threadIdx.x == 0) {
    atomicAdd(lsum, rsd[0] + rsd[1] + rsd[2] + rsd[3]);
    atomicAdd(nval, rid[0] + rid[1] + rid[2] + rid[3]);
  }
}

// Parallel fallback phase A: unit u = (f, j) -> row fbrows[f], candidates
// [j*256, j*256+256). One candidate/thread; 8 independent FMA chains (ILP).
__global__ __launch_bounds__(256) void kfallA(const short* __restrict__ emb16,
                                              const int* __restrict__ lab,
                                              const int* __restrict__ fbcnt,
                                              const int* __restrict__ fbrows,
                                              float* __restrict__ fbpart) {
  int nfb = *fbcnt;
  if (nfb > 2048) nfb = 2048;
  int nunits = nfb * 32;
  __shared__ short remb[512];
  __shared__ float sims[256];
  int t = threadIdx.x;
  for (int u = blockIdx.x; u < nunits; u += gridDim.x) {
    int f = u >> 5, j = u & 31;
    int row = fbrows[f];
    int rl = lab[row];
    __syncthreads();  // prior iteration's reads of remb/sims complete
    if (t < 64) *(v8s*)&remb[t * 8] = *(const v8s*)(emb16 + (size_t)row * 512 + t * 8);
    __syncthreads();
    int c = j * 256 + t;
    float sz[8];
#pragma unroll
    for (int z = 0; z < 8; ++z) sz[z] = 0.f;
#pragma unroll 4
    for (int q = 0; q < 64; ++q) {
      v8s e = *(const v8s*)(emb16 + (size_t)c * 512 + q * 8);
      v8s r = *(const v8s*)&remb[q * 8];
#pragma unroll
      for (int z = 0; z < 8; ++z) sz[z] += bf2f(e[z]) * bf2f(r[z]);
    }
    float s = ((sz[0] + sz[1]) + (sz[2] + sz[3])) + ((sz[4] + sz[5]) + (sz[6] + sz[7]));
    sims[t] = (lab[c] != rl) ? s : NEGV;
    __syncthreads();
    if (t < 64) {
      float M[16];
#pragma unroll
      for (int k = 0; k < 16; ++k) M[k] = NEGV;
      M[0] = sims[t]; M[1] = sims[64 + t]; M[2] = sims[128 + t]; M[3] = sims[192 + t];
      sort16d(M);
      xmerge16(M, 1); xmerge16(M, 2); xmerge16(M, 4);
      xmerge16(M, 8); xmerge16(M, 16); xmerge16(M, 32);
      if (t == 0) {
#pragma unroll
        for (int k = 0; k < 16; ++k) fbpart[(size_t)(f * 32 + j) * 16 + k] = M[k];
      }
    }
  }
}

// Final kernel: finish fallback rows (merge 32 partials each, LSE, accumulate)
// then write out = (lsum + fb_sum) / nval. Single block.
__global__ __launch_bounds__(256) void kout(const short* __restrict__ emb16,
                                            const int* __restrict__ lab,
                                            const int* __restrict__ fbcnt,
                                            const int* __restrict__ fbrows,
                                            const float* __restrict__ fbpart,
                                            const float* __restrict__ pterm,
                                            const float* lsum, const int* nval,
                                            float* out) {
  __shared__ float fsum[256];
  int t = threadIdx.x;
  int nfb = *fbcnt;
  float acc = 0.f;
  for (int f = t; f < nfb; f += 256) {
    int row = fbrows[f];
    float R[16];
    if (f < 2048) {
#pragma unroll
      for (int k = 0; k < 16; ++k) R[k] = fbpart[(size_t)(f * 32) * 16 + k];
      for (int j = 1; j < 32; ++j) {
        float M[16];
#pragma unroll
        for (int k = 0; k < 16; ++k) M[k] = fbpart[(size_t)(f * 32 + j) * 16 + k];
        mergeld(R, M);
      }
    } else {
      // correctness guard; never expected to execute
      int rl = lab[row];
      float L[16];
#pragma unroll
      for (int k = 0; k < 16; ++k) L[k] = NEGV;
      for (int c = 0; c < 8192; ++c) {
        if (lab[c] == rl) continue;
        float s = 0.f;
        for (int q = 0; q < 64; ++q) {
          v8s e = *(const v8s*)(emb16 + (size_t)c * 512 + q * 8);
          v8s r = *(const v8s*)(emb16 + (size_t)row * 512 + q * 8);
#pragma unroll
          for (int z = 0; z < 8; ++z) s += bf2f(e[z]) * bf2f(r[z]);
        }
        if (s > L[0]) ins16(L, s);
      }
#pragma unroll
      for (int k = 0; k < 16; ++k) R[k] = L[15 - k];
    }
    float m = R[0] / TEMPV;
    float se = 0.f;
#pragma unroll
    for (int k = 0; k < 16; ++k)
      if (R[k] > -1e29f) se += expf(R[k] / TEMPV - m);
    acc += m + logf(se) - pterm[row];
  }
  fsum[t] = acc;
  __syncthreads();
  if (t == 0) {
    float s = *lsum;
    for (int k = 0; k < 256; ++k) s += fsum[k];
    int n = *nval;
    out[0] = s / (float)(n > 0 ? n : 1);
  }
}

extern "C" void kernel_launch(void* const* d_in, const int* in_sizes, int n_in,
                              void* d_out, int out_size, void* d_ws, size_t ws_size,
                              hipStream_t stream) {
  const float* emb = (const float*)d_in[0];
  const int* lab = (const int*)d_in[1];
  float* out = (float*)d_out;

  char* wsb = (char*)d_ws;
  short* emb16 = (short*)wsb;                       // 8,388,608
  int* hist = (int*)(wsb + 8388608);                // 8,192
  int* start = (int*)(wsb + 8396800);               // 8,192
  int* rows = (int*)(wsb + 8404992);                // 32,768
  float* pmin = (float*)(wsb + 8437760);            // 32,768
  float* pterm = (float*)(wsb + 8470528);           // 32,768
  int* valid = (int*)(wsb + 8503296);               // 32,768
  float* LsemiW = (float*)(wsb + 8536064);          // 4,194,304 (8 partials)
  int* fbcnt = (int*)(wsb + 12730368);              // 4 (+pad 64)
  int* fbrows = (int*)(wsb + 12730432);             // 32,768
  float* fbpart = (float*)(wsb + 12763200);         // 4,194,304
  float* lsum = (float*)(wsb + 16957504);           // 4
  int* nval = (int*)(wsb + 16957508);               // 4

  kconvh<<<4097, 256, 0, stream>>>(emb, emb16, lab, hist, start, rows, lsum, nval, fbcnt);
  kpos2<<<2048, 256, 0, stream>>>(emb16, lab, hist, start, rows, pmin, pterm, valid);
  kgemm<<<1024, 256, 0, stream>>>(emb16, lab, pmin, LsemiW);
  kfin<<<32, 256, 0, stream>>>(LsemiW, pterm, valid, lsum, nval, fbcnt, fbrows);
  kfallA<<<256, 256, 0, stream>>>(emb16, lab, fbcnt, fbrows, fbpart);
  kout<<<1, 256, 0, stream>>>(emb16, lab, fbcnt, fbrows, fbpart, pterm, lsum, nval, out);
}